// Round 18
// baseline (65.496 us; speedup 1.0000x reference)
//
#include <hip/hip_runtime.h>
#include <hip/hip_bf16.h>

#define N2 16384
#define D  128
#define PANEL 32768                       // bytes per 128x128 bf16 panel
#define SQC1 1.69864360258810896f         // sqrt(2*log2(e)), folded into zn
#define LN2  0.69314718055994530942f

typedef __bf16 bf16x8 __attribute__((ext_vector_type(8)));
typedef float  f32x16 __attribute__((ext_vector_type(16)));

#if __has_builtin(__builtin_amdgcn_exp2f)
#define EXP2(x) __builtin_amdgcn_exp2f(x)
#else
#define EXP2(x) exp2f(x)
#endif

__device__ __forceinline__ unsigned short f2bf(float f) {
    union { float f; unsigned u; } v; v.f = f;
    unsigned r = v.u + 0x7fffu + ((v.u >> 16) & 1u);
    return (unsigned short)(r >> 16);
}

// stage one 32KB panel global->LDS via global_load_lds width=16.
// LDS dest linear; XOR swizzle on the GLOBAL source (involution on 16B
// granules, now 16-deep for the 32-row read groups of the 32x32 MFMA):
// reads use byte ^ ((row&15)<<4), row = byte>>8. (rule #21)
__device__ __forceinline__ void stage_panel(const char* __restrict__ g,
                                            char* lds, int tid) {
    const int wid = tid >> 6, lane = tid & 63;
    #pragma unroll
    for (int i = 0; i < 8; ++i) {
        int off = (wid << 13) + (i << 10) + (lane << 4);
        int src = off ^ (((off >> 8) & 15) << 4);
        __builtin_amdgcn_global_load_lds(
            (const __attribute__((address_space(1))) unsigned*)(g + src),
            (__attribute__((address_space(3))) unsigned*)(lds + (wid << 13) + (i << 10)),
            16, 0, 0);
    }
}

// ---------- kernel 1: row L2-normalize -> bf16 sqrt(C1)*zn, + zero rowsum/out ----------
__global__ void k_norm(const float* __restrict__ z, unsigned short* __restrict__ zn,
                       float* __restrict__ rowsum, float* __restrict__ out) {
    if (blockIdx.x < 64) rowsum[blockIdx.x * 256 + threadIdx.x] = 0.f;
    if (blockIdx.x == 64 && threadIdx.x == 0) out[0] = 0.f;
    int row  = blockIdx.x * 4 + (threadIdx.x >> 6);
    int lane = threadIdx.x & 63;
    const float2 v = ((const float2*)(z + (size_t)row * D))[lane];
    float ss = v.x * v.x + v.y * v.y;
    #pragma unroll
    for (int m = 1; m < 64; m <<= 1) ss += __shfl_xor(ss, m);
    float inv = SQC1 / fmaxf(sqrtf(ss), 1e-12f);
    ushort2 o; o.x = f2bf(v.x * inv); o.y = f2bf(v.y * inv);
    ((ushort2*)(zn + (size_t)row * D))[lane] = o;
}

// ---------- kernel 2: R17 skeleton, 32x32x16 MFMA ----------
// block (c, ti): s in [16c, 16c+16) (+s=64 for c==3, ti<64). jt=(ti+s)&127.
// Wave tile 64x64 = 2x2 of 32x32 outputs; 32 MFMA/tile (was 64).
// A-frag: lane holds row=lane&31, k=(lane>>5)*8+[0..7] (bf16x8 @ 16B).
// C/D:    col=lane&31, row=(reg&3)+8*(reg>>2)+4*(lane>>5) [m74/m101].
__global__ __launch_bounds__(256, 2)
void k_sim(const unsigned short* __restrict__ zn, float* __restrict__ rowsum) {
    __shared__ unsigned short ls[2][PANEL / 2];
    char* ls0 = (char*)&ls[0][0];
    char* ls1 = (char*)&ls[1][0];

    const int tileI = blockIdx.y;
    const int sBase = blockIdx.x * 16;
    const int nt = (blockIdx.x == 3 && tileI < 64) ? 17 : 16;
    const int tid  = threadIdx.x;
    const int lane = tid & 63, wid = tid >> 6;
    const int wr = wid >> 1, wc = wid & 1;          // 2x2 wave grid, 64x64 each
    const int l32 = lane & 31, h = lane >> 5;       // 32-lane row/col id, half id
    const char* znb = (const char*)zn;
    const f32x16 ZERO16 = {0.f,0.f,0.f,0.f,0.f,0.f,0.f,0.f,
                           0.f,0.f,0.f,0.f,0.f,0.f,0.f,0.f};

    // prologue: stage A(ti) -> ls0, B(s=sBase) -> ls1
    stage_panel(znb + (size_t)tileI * PANEL, ls0, tid);
    stage_panel(znb + (size_t)((tileI + sBase) & 127) * PANEL, ls1, tid);
    asm volatile("s_waitcnt vmcnt(8)" ::: "memory");   // A landed
    __builtin_amdgcn_s_barrier();

    // A fragments -> registers: [kc][mi], kc=K/16 (8), mi=2 (32-row tiles)
    bf16x8 af[8][2];
    #pragma unroll
    for (int kc = 0; kc < 8; ++kc)
        #pragma unroll
        for (int mi = 0; mi < 2; ++mi) {
            int row = wr * 64 + mi * 32 + l32;
            int d = row * 256 + kc * 32 + h * 16;
            af[kc][mi] = *(const bf16x8*)(ls0 + (d ^ ((row & 15) << 4)));
        }
    asm volatile("s_waitcnt lgkmcnt(0)" ::: "memory");
    __builtin_amdgcn_s_barrier();                      // ls0 now reusable

    float rs[2][16];                                   // [mi][reg] row partials
    #pragma unroll
    for (int mi = 0; mi < 2; ++mi)
        #pragma unroll
        for (int r = 0; r < 16; ++r) rs[mi][r] = 0.f;

    for (int t = 0; t < nt; ++t) {
        const int s  = sBase + t;
        const int jt = (tileI + s) & 127;
        char* rbuf = (t & 1) ? ls0 : ls1;              // B(s)
        char* sbuf = (t & 1) ? ls1 : ls0;              // B(s+1) dest
        if (t < nt - 1) {
            stage_panel(znb + (size_t)((tileI + s + 1) & 127) * PANEL, sbuf, tid);
            asm volatile("s_waitcnt vmcnt(8)" ::: "memory");  // B(s) landed
        } else {
            asm volatile("s_waitcnt vmcnt(0)" ::: "memory");
        }
        __builtin_amdgcn_s_barrier();

        bf16x8 bfr[8][2];                              // [kc][ni]
        #pragma unroll
        for (int kc = 0; kc < 8; ++kc)
            #pragma unroll
            for (int ni = 0; ni < 2; ++ni) {
                int row = wc * 64 + ni * 32 + l32;
                int d = row * 256 + kc * 32 + h * 16;
                bfr[kc][ni] = *(const bf16x8*)(rbuf + (d ^ ((row & 15) << 4)));
            }
        asm volatile("s_waitcnt lgkmcnt(0)" ::: "memory");
        __builtin_amdgcn_s_barrier();                  // rbuf free for next stage

        f32x16 acc[2][2];
        #pragma unroll
        for (int mi = 0; mi < 2; ++mi)
            #pragma unroll
            for (int ni = 0; ni < 2; ++ni)
                acc[mi][ni] = __builtin_amdgcn_mfma_f32_32x32x16_bf16(
                    af[0][mi], bfr[0][ni], ZERO16, 0, 0, 0);
        #pragma unroll
        for (int kc = 1; kc < 8; ++kc)
            #pragma unroll
            for (int mi = 0; mi < 2; ++mi)
                #pragma unroll
                for (int ni = 0; ni < 2; ++ni)
                    acc[mi][ni] = __builtin_amdgcn_mfma_f32_32x32x16_bf16(
                        af[kc][mi], bfr[kc][ni], acc[mi][ni], 0, 0, 0);

        // epilogue: e = exp2(acc) = exp(sim); C row = (r&3)+8*(r>>2)+4*h
        if (s == 0) {
            // diagonal tile: mask self-sim, row sums only
            #pragma unroll
            for (int mi = 0; mi < 2; ++mi)
                #pragma unroll
                for (int r = 0; r < 16; ++r) {
                    int li = wr * 64 + mi * 32 + (r & 3) + 8 * (r >> 2) + 4 * h;
                    float a = 0.f;
                    #pragma unroll
                    for (int ni = 0; ni < 2; ++ni) {
                        int lj = wc * 64 + ni * 32 + l32;
                        float e = EXP2(acc[mi][ni][r]);
                        a += (li == lj) ? 0.f : e;
                    }
                    rs[mi][r] += a;
                }
        } else {
            float cs0 = 0.f, cs1 = 0.f;                // col partials (col = l32)
            #pragma unroll
            for (int mi = 0; mi < 2; ++mi)
                #pragma unroll
                for (int r = 0; r < 16; ++r) {
                    float e0 = EXP2(acc[mi][0][r]);
                    float e1 = EXP2(acc[mi][1][r]);
                    rs[mi][r] += e0 + e1;
                    cs0 += e0; cs1 += e1;
                }
            // column flush: combine the two lane-halves (rows split by h)
            cs0 += __shfl_xor(cs0, 32);
            cs1 += __shfl_xor(cs1, 32);
            if (h == 0) {
                atomicAdd(&rowsum[jt * 128 + wc * 64 + l32], cs0);
                atomicAdd(&rowsum[jt * 128 + wc * 64 + 32 + l32], cs1);
            }
        }
    }

    // final: row sums -> reduce across the 32 column-lanes, atomics from lane 0 of each half
    #pragma unroll
    for (int mi = 0; mi < 2; ++mi)
        #pragma unroll
        for (int r = 0; r < 16; ++r) {
            float v = rs[mi][r];
            v += __shfl_xor(v, 1);
            v += __shfl_xor(v, 2);
            v += __shfl_xor(v, 4);
            v += __shfl_xor(v, 8);
            v += __shfl_xor(v, 16);
            if (l32 == 0)
                atomicAdd(&rowsum[tileI * 128 + wr * 64 + mi * 32
                                  + (r & 3) + 8 * (r >> 2) + 4 * h], v);
        }
}

// ---------- kernel 3: fused loss + mean (R3-verbatim) ----------
// mean loss = (1/N2) * [ sum_i ln(rowsum_i) - ln2 * sum_{i,k} zn'[i][k]*zn'[i^1][k] ]
__global__ void k_loss_reduce(const unsigned short* __restrict__ zn,
                              const float* __restrict__ rowsum,
                              float* __restrict__ out) {
    const int tid = threadIdx.x + blockIdx.x * 256;   // 64 blocks x 256
    float p = 0.f;
    const bf16x8* v8 = (const bf16x8*)zn;
    for (int v = tid; v < N2 * D / 8; v += 64 * 256) {
        bf16x8 a = v8[v];
        bf16x8 b = v8[v ^ 16];                        // row i^1, same k-slice
        #pragma unroll
        for (int e = 0; e < 8; ++e) p += (float)a[e] * (float)b[e];
    }
    float part = logf(rowsum[tid]) - LN2 * p;         // exactly one row per thread

    __shared__ float sm[4];
    #pragma unroll
    for (int m = 1; m < 64; m <<= 1) part += __shfl_xor(part, m);
    if ((threadIdx.x & 63) == 0) sm[threadIdx.x >> 6] = part;
    __syncthreads();
    if (threadIdx.x == 0)
        atomicAdd(out, (sm[0] + sm[1] + sm[2] + sm[3]) * (1.0f / (float)N2));
}

extern "C" void kernel_launch(void* const* d_in, const int* in_sizes, int n_in,
                              void* d_out, int out_size, void* d_ws, size_t ws_size,
                              hipStream_t stream) {
    const float* z = (const float*)d_in[0];
    float* out = (float*)d_out;

    unsigned short* zn = (unsigned short*)d_ws;                       // 4 MiB
    float* rowsum = (float*)((char*)d_ws + (size_t)N2 * D * 2);       // 64 KiB

    k_norm<<<N2 / 4, 256, 0, stream>>>(z, zn, rowsum, out);
    dim3 grid(4, 128);                                                // s-chunks x i-tiles
    k_sim<<<grid, 256, 0, stream>>>(zn, rowsum);
    k_loss_reduce<<<64, 256, 0, stream>>>(zn, rowsum, out);
}

// Round 19
// 63.590 us; speedup vs baseline: 1.0300x; 1.0300x over previous
//
#include <hip/hip_runtime.h>
#include <hip/hip_bf16.h>

#define N2 16384
#define D  128
#define PANEL 32768                       // bytes per 128x128 bf16 panel
#define SQC1 1.69864360258810896f         // sqrt(2*log2(e)), folded into zn
#define LN2  0.69314718055994530942f

typedef __bf16 bf16x8 __attribute__((ext_vector_type(8)));
typedef float  f32x4  __attribute__((ext_vector_type(4)));

#if __has_builtin(__builtin_amdgcn_exp2f)
#define EXP2(x) __builtin_amdgcn_exp2f(x)
#else
#define EXP2(x) exp2f(x)
#endif

__device__ __forceinline__ unsigned short f2bf(float f) {
    union { float f; unsigned u; } v; v.f = f;
    unsigned r = v.u + 0x7fffu + ((v.u >> 16) & 1u);
    return (unsigned short)(r >> 16);
}

// stage one 32KB panel global->LDS via global_load_lds width=16.
// LDS dest linear; XOR swizzle on the GLOBAL source (involution); reads
// use byte ^ ((row&7)<<4). (rule #21)
__device__ __forceinline__ void stage_panel(const char* __restrict__ g,
                                            char* lds, int tid) {
    const int wid = tid >> 6, lane = tid & 63;
    #pragma unroll
    for (int i = 0; i < 8; ++i) {
        int off = (wid << 13) + (i << 10) + (lane << 4);
        int src = off ^ (((off >> 8) & 7) << 4);
        __builtin_amdgcn_global_load_lds(
            (const __attribute__((address_space(1))) unsigned*)(g + src),
            (__attribute__((address_space(3))) unsigned*)(lds + (wid << 13) + (i << 10)),
            16, 0, 0);
    }
}

// ---------- kernel 1: row L2-normalize -> bf16 sqrt(C1)*zn, + zero rowsum/out ----------
__global__ void k_norm(const float* __restrict__ z, unsigned short* __restrict__ zn,
                       float* __restrict__ rowsum, float* __restrict__ out) {
    if (blockIdx.x < 64) rowsum[blockIdx.x * 256 + threadIdx.x] = 0.f;
    if (blockIdx.x == 64 && threadIdx.x == 0) out[0] = 0.f;
    int row  = blockIdx.x * 4 + (threadIdx.x >> 6);
    int lane = threadIdx.x & 63;
    const float2 v = ((const float2*)(z + (size_t)row * D))[lane];
    float ss = v.x * v.x + v.y * v.y;
    #pragma unroll
    for (int m = 1; m < 64; m <<= 1) ss += __shfl_xor(ss, m);
    float inv = SQC1 / fmaxf(sqrtf(ss), 1e-12f);
    ushort2 o; o.x = f2bf(v.x * inv); o.y = f2bf(v.y * inv);
    ((ushort2*)(zn + (size_t)row * D))[lane] = o;
}

// ---------- kernel 2: R17 skeleton + deferred col-atomics ----------
// block (c, ti): s in [16c, 16c+16) (+s=64 for c==3, ti<64). jt=(ti+s)&127.
// CHANGE vs R17 (one mechanism): col sums are reduced into regs (csp) in the
// epilogue and flushed at the TOP of the next iteration, after stage-issue.
// vmcnt(12) leaves {8 stage + 4 atomics} in flight and drains only stage(t)
// -> the atomics get a full tile (~5k cyc) of cover instead of being
// serially drained by R17's vmcnt(8) with ~0 cycles of flight.
__global__ __launch_bounds__(256, 2)
void k_sim(const unsigned short* __restrict__ zn, float* __restrict__ rowsum) {
    __shared__ unsigned short ls[2][PANEL / 2];
    char* ls0 = (char*)&ls[0][0];
    char* ls1 = (char*)&ls[1][0];

    const int tileI = blockIdx.y;
    const int sBase = blockIdx.x * 16;
    const int nt = (blockIdx.x == 3 && tileI < 64) ? 17 : 16;
    const int tid  = threadIdx.x;
    const int lane = tid & 63, wid = tid >> 6;
    const int wr = wid >> 1, wc = wid & 1;          // 2x2 wave grid, 64x64 each
    const int l16 = lane & 15, lg = lane >> 4;
    const char* znb = (const char*)zn;
    const f32x4 ZERO = {0.f, 0.f, 0.f, 0.f};

    // prologue: stage A(ti) -> ls0, B(s=sBase) -> ls1
    stage_panel(znb + (size_t)tileI * PANEL, ls0, tid);
    stage_panel(znb + (size_t)((tileI + sBase) & 127) * PANEL, ls1, tid);
    asm volatile("s_waitcnt vmcnt(8)" ::: "memory");   // A landed
    __builtin_amdgcn_s_barrier();

    // A fragments -> registers (reused for all tiles)
    bf16x8 af[4][4];                                   // [kk][m]
    #pragma unroll
    for (int kk = 0; kk < 4; ++kk)
        #pragma unroll
        for (int m = 0; m < 4; ++m) {
            int row = wr * 64 + m * 16 + l16;
            int d = row * 256 + kk * 64 + lg * 16;
            af[kk][m] = *(const bf16x8*)(ls0 + (d ^ ((row & 7) << 4)));
        }
    asm volatile("s_waitcnt lgkmcnt(0)" ::: "memory");
    __builtin_amdgcn_s_barrier();                      // ls0 now reusable

    float rs[4][4];
    #pragma unroll
    for (int m = 0; m < 4; ++m)
        #pragma unroll
        for (int r = 0; r < 4; ++r) rs[m][r] = 0.f;

    float csp[4] = {0.f, 0.f, 0.f, 0.f};              // deferred col sums (reduced)
    int jtp = tileI;                                   // dummy first flush adds 0.0

    for (int t = 0; t < nt; ++t) {
        const int s  = sBase + t;
        const int jt = (tileI + s) & 127;
        char* rbuf = (t & 1) ? ls0 : ls1;              // B(s)
        char* sbuf = (t & 1) ? ls1 : ls0;              // B(s+1) dest

        if (t < nt - 1)
            stage_panel(znb + (size_t)((tileI + s + 1) & 127) * PANEL, sbuf, tid);
        // flush PREVIOUS tile's col sums (4 atomic VM ops, uniform every iter)
        #pragma unroll
        for (int n = 0; n < 4; ++n)
            if (lg == 0)
                atomicAdd(&rowsum[jtp * 128 + wc * 64 + n * 16 + l16], csp[n]);
        // counted drain of stage(t): leave {stage(t+1)[8] + atomics[4]} in flight
        if (t < nt - 1) { asm volatile("s_waitcnt vmcnt(12)" ::: "memory"); }
        else           { asm volatile("s_waitcnt vmcnt(4)"  ::: "memory"); }
        __builtin_amdgcn_s_barrier();

        bf16x8 bfr[4][4];                              // [kk][n]
        #pragma unroll
        for (int kk = 0; kk < 4; ++kk)
            #pragma unroll
            for (int n = 0; n < 4; ++n) {
                int row = wc * 64 + n * 16 + l16;
                int d = row * 256 + kk * 64 + lg * 16;
                bfr[kk][n] = *(const bf16x8*)(rbuf + (d ^ ((row & 7) << 4)));
            }
        asm volatile("s_waitcnt lgkmcnt(0)" ::: "memory");
        __builtin_amdgcn_s_barrier();                  // rbuf free for next stage

        f32x4 acc[4][4];
        #pragma unroll
        for (int m = 0; m < 4; ++m)
            #pragma unroll
            for (int n = 0; n < 4; ++n)
                acc[m][n] = __builtin_amdgcn_mfma_f32_16x16x32_bf16(af[0][m], bfr[0][n], ZERO, 0, 0, 0);
        #pragma unroll
        for (int kk = 1; kk < 4; ++kk)
            #pragma unroll
            for (int m = 0; m < 4; ++m)
                #pragma unroll
                for (int n = 0; n < 4; ++n)
                    acc[m][n] = __builtin_amdgcn_mfma_f32_16x16x32_bf16(af[kk][m], bfr[kk][n], acc[m][n], 0, 0, 0);

        // epilogue: e = exp2(acc) = exp(sim); col sums reduced into csp,
        // flushed next iteration (deferred).
        if (s == 0) {
            // diagonal tile: mask self-sim, row sums only; csp stays 0
            #pragma unroll
            for (int m = 0; m < 4; ++m)
                #pragma unroll
                for (int r = 0; r < 4; ++r) {
                    int li = wr * 64 + m * 16 + lg * 4 + r;
                    float a = 0.f;
                    #pragma unroll
                    for (int n = 0; n < 4; ++n) {
                        int lj = wc * 64 + n * 16 + l16;
                        float e = EXP2(acc[m][n][r]);
                        a += (li == lj) ? 0.f : e;
                    }
                    rs[m][r] += a;
                }
            csp[0] = csp[1] = csp[2] = csp[3] = 0.f;
        } else {
            float cs[4] = {0.f, 0.f, 0.f, 0.f};
            #pragma unroll
            for (int m = 0; m < 4; ++m)
                #pragma unroll
                for (int r = 0; r < 4; ++r) {
                    float a = 0.f;
                    #pragma unroll
                    for (int n = 0; n < 4; ++n) {
                        float e = EXP2(acc[m][n][r]);
                        a += e;
                        cs[n] += e;
                    }
                    rs[m][r] += a;
                }
            // reduce col partials over the 4 lg row-groups now; flush next top
            #pragma unroll
            for (int n = 0; n < 4; ++n) {
                float v = cs[n];
                v += __shfl_xor(v, 16);
                v += __shfl_xor(v, 32);
                csp[n] = v;
            }
        }
        jtp = jt;
    }

    // trailing flush: last tile's col sums
    #pragma unroll
    for (int n = 0; n < 4; ++n)
        if (lg == 0)
            atomicAdd(&rowsum[jtp * 128 + wc * 64 + n * 16 + l16], csp[n]);

    // final: row sums -> reduce across 16 column-lanes, one atomic/row
    #pragma unroll
    for (int m = 0; m < 4; ++m)
        #pragma unroll
        for (int r = 0; r < 4; ++r) {
            float v = rs[m][r];
            v += __shfl_xor(v, 1);
            v += __shfl_xor(v, 2);
            v += __shfl_xor(v, 4);
            v += __shfl_xor(v, 8);
            if (l16 == 0)
                atomicAdd(&rowsum[tileI * 128 + wr * 64 + m * 16 + lg * 4 + r], v);
        }
}

// ---------- kernel 3: fused loss + mean (R3-verbatim) ----------
// mean loss = (1/N2) * [ sum_i ln(rowsum_i) - ln2 * sum_{i,k} zn'[i][k]*zn'[i^1][k] ]
__global__ void k_loss_reduce(const unsigned short* __restrict__ zn,
                              const float* __restrict__ rowsum,
                              float* __restrict__ out) {
    const int tid = threadIdx.x + blockIdx.x * 256;   // 64 blocks x 256
    float p = 0.f;
    const bf16x8* v8 = (const bf16x8*)zn;
    for (int v = tid; v < N2 * D / 8; v += 64 * 256) {
        bf16x8 a = v8[v];
        bf16x8 b = v8[v ^ 16];                        // row i^1, same k-slice
        #pragma unroll
        for (int e = 0; e < 8; ++e) p += (float)a[e] * (float)b[e];
    }
    float part = logf(rowsum[tid]) - LN2 * p;         // exactly one row per thread

    __shared__ float sm[4];
    #pragma unroll
    for (int m = 1; m < 64; m <<= 1) part += __shfl_xor(part, m);
    if ((threadIdx.x & 63) == 0) sm[threadIdx.x >> 6] = part;
    __syncthreads();
    if (threadIdx.x == 0)
        atomicAdd(out, (sm[0] + sm[1] + sm[2] + sm[3]) * (1.0f / (float)N2));
}

extern "C" void kernel_launch(void* const* d_in, const int* in_sizes, int n_in,
                              void* d_out, int out_size, void* d_ws, size_t ws_size,
                              hipStream_t stream) {
    const float* z = (const float*)d_in[0];
    float* out = (float*)d_out;

    unsigned short* zn = (unsigned short*)d_ws;                       // 4 MiB
    float* rowsum = (float*)((char*)d_ws + (size_t)N2 * D * 2);       // 64 KiB

    k_norm<<<N2 / 4, 256, 0, stream>>>(z, zn, rowsum, out);
    dim3 grid(4, 128);                                                // s-chunks x i-tiles
    k_sim<<<grid, 256, 0, stream>>>(zn, rowsum);
    k_loss_reduce<<<64, 256, 0, stream>>>(zn, rowsum, out);
}